// Round 8
// baseline (444.896 us; speedup 1.0000x reference)
//
#include <hip/hip_runtime.h>
#include <math.h>

#define BB 512
#define SS 16384
#define TPIF 6.28318530717958647692f

// separate re/im float arrays in LDS; pad 1 per 32 elements (low-conflict,
// measured 5.8e6 vs 3.1e7 for float2/pad16 in R3-R7)
#define PAD32(i) ((i) + ((i) >> 5) + ((i) >> 10))
#define NPAD 16912   // PAD32(16383)=16909 < 16912

// base-4 digit reversal of 14-bit index (7 digits)
__device__ __forceinline__ int digrev4(int n) {
    unsigned x = __brev((unsigned)n) >> (32 - 14);
    return (int)(((x & 0x1555u) << 1) | ((x >> 1) & 0x1555u));
}

// ---------------------------------------------------------------------------
// Single-stage radix-4 passes, 1024 threads, 4 butterflies/thread.
// DIF: L descending 16384..4, twiddle W_L^p on outputs -> digit-rev output.
// DIT: L ascending 4..16384, twiddle W_L^p on inputs, rev input -> natural.
// (both directions verified end-to-end in R7)
// ---------------------------------------------------------------------------
template <int SGN, int LOG2L>
__device__ __forceinline__ void stage_dif(float* re, float* im, int t) {
    constexpr int L = 1 << LOG2L;
    constexpr int Q = L >> 2;
    const float sg = (float)SGN;
    #pragma unroll
    for (int j = 0; j < 4; ++j) {
        const int b = t + (j << 10);
        const int p = b & (Q - 1);
        const int i0 = ((b >> (LOG2L - 2)) << LOG2L) + p;
        const int a0 = PAD32(i0), a1 = PAD32(i0 + Q), a2 = PAD32(i0 + 2 * Q), a3 = PAD32(i0 + 3 * Q);
        float z0r = re[a0], z0i = im[a0];
        float z1r = re[a1], z1i = im[a1];
        float z2r = re[a2], z2i = im[a2];
        float z3r = re[a3], z3i = im[a3];
        float t0r = z0r + z2r, t0i = z0i + z2i;
        float t1r = z0r - z2r, t1i = z0i - z2i;
        float t2r = z1r + z3r, t2i = z1i + z3i;
        float t3r = z1r - z3r, t3i = z1i - z3i;
        float b0r = t0r + t2r, b0i = t0i + t2i;
        float b2r = t0r - t2r, b2i = t0i - t2i;
        float b1r = t1r - sg * t3i, b1i = t1i + sg * t3r;
        float b3r = t1r + sg * t3i, b3i = t1i - sg * t3r;
        const float arev = sg * (float)p * (1.0f / (float)L);   // revolutions
        const float c1 = __builtin_amdgcn_cosf(arev);
        const float s1 = __builtin_amdgcn_sinf(arev);
        const float c2 = c1 * c1 - s1 * s1, s2 = 2.0f * c1 * s1;
        const float c3 = c1 * c2 - s1 * s2, s3 = c1 * s2 + s1 * c2;
        re[a0] = b0r;                    im[a0] = b0i;
        re[a1] = b1r * c1 - b1i * s1;    im[a1] = b1r * s1 + b1i * c1;
        re[a2] = b2r * c2 - b2i * s2;    im[a2] = b2r * s2 + b2i * c2;
        re[a3] = b3r * c3 - b3i * s3;    im[a3] = b3r * s3 + b3i * c3;
    }
    __syncthreads();
}

template <int SGN, int LOG2L>
__device__ __forceinline__ void stage_dit(float* re, float* im, int t) {
    constexpr int L = 1 << LOG2L;
    constexpr int Q = L >> 2;
    const float sg = (float)SGN;
    #pragma unroll
    for (int j = 0; j < 4; ++j) {
        const int b = t + (j << 10);
        const int p = b & (Q - 1);
        const int i0 = ((b >> (LOG2L - 2)) << LOG2L) + p;
        const int a0 = PAD32(i0), a1 = PAD32(i0 + Q), a2 = PAD32(i0 + 2 * Q), a3 = PAD32(i0 + 3 * Q);
        float z0r = re[a0], z0i = im[a0];
        float z1r = re[a1], z1i = im[a1];
        float z2r = re[a2], z2i = im[a2];
        float z3r = re[a3], z3i = im[a3];
        const float arev = sg * (float)p * (1.0f / (float)L);
        const float c1 = __builtin_amdgcn_cosf(arev);
        const float s1 = __builtin_amdgcn_sinf(arev);
        const float c2 = c1 * c1 - s1 * s1, s2 = 2.0f * c1 * s1;
        const float c3 = c1 * c2 - s1 * s2, s3 = c1 * s2 + s1 * c2;
        float a1r = z1r * c1 - z1i * s1, a1i = z1r * s1 + z1i * c1;
        float a2r = z2r * c2 - z2i * s2, a2i = z2r * s2 + z2i * c2;
        float a3r = z3r * c3 - z3i * s3, a3i = z3r * s3 + z3i * c3;
        float t0r = z0r + a2r, t0i = z0i + a2i;
        float t1r = z0r - a2r, t1i = z0i - a2i;
        float t2r = a1r + a3r, t2i = a1i + a3i;
        float t3r = a1r - a3r, t3i = a1i - a3i;
        re[a0] = t0r + t2r;       im[a0] = t0i + t2i;
        re[a2] = t0r - t2r;       im[a2] = t0i - t2i;
        re[a1] = t1r - sg * t3i;  im[a1] = t1i + sg * t3r;
        re[a3] = t1r + sg * t3i;  im[a3] = t1i - sg * t3r;
    }
    __syncthreads();
}

// ---------------------------------------------------------------------------
// K1: Pearson + MI per row (256 threads; R1's proven kernels fused; global
// data re-read between passes, L3-resident)
// ---------------------------------------------------------------------------
__global__ __launch_bounds__(256) void k_stats(const float* __restrict__ pred,
                                               const float* __restrict__ targ,
                                               const int* __restrict__ ip,
                                               float* __restrict__ wpear,
                                               float* __restrict__ wnmi) {
    __shared__ double dpart[4 * 5];
    __shared__ float fpart[4 * 4];
    __shared__ float sbounds[4];
    __shared__ int   subhist[400];
    __shared__ float hxm[10], hym[10];
    __shared__ float mterm[128];
    const int row = blockIdx.x;
    const int t = threadIdx.x;
    const int w = t >> 6;
    const int lane = t & 63;
    const float* x = pred + (size_t)ip[0] * (size_t)BB * SS + (size_t)row * SS;
    const float* y = targ + (size_t)row * SS;

    // ---- pass 1: Pearson sums (fp64) + min/max
    {
        double sx = 0, sy = 0, sxy = 0, sxx = 0, syy = 0;
        float xmn = 1e30f, xmx = -1e30f, ymn = 1e30f, ymx = -1e30f;
        for (int n = t; n < SS; n += 256) {
            float a = x[n], b = y[n];
            sx += (double)a; sy += (double)b;
            sxy += (double)a * (double)b;
            sxx += (double)a * (double)a;
            syy += (double)b * (double)b;
            xmn = fminf(xmn, a); xmx = fmaxf(xmx, a);
            ymn = fminf(ymn, b); ymx = fmaxf(ymx, b);
        }
        #pragma unroll
        for (int o = 32; o > 0; o >>= 1) {
            sx += __shfl_down(sx, o, 64);  sy += __shfl_down(sy, o, 64);
            sxy += __shfl_down(sxy, o, 64);
            sxx += __shfl_down(sxx, o, 64); syy += __shfl_down(syy, o, 64);
            xmn = fminf(xmn, __shfl_down(xmn, o, 64));
            xmx = fmaxf(xmx, __shfl_down(xmx, o, 64));
            ymn = fminf(ymn, __shfl_down(ymn, o, 64));
            ymx = fmaxf(ymx, __shfl_down(ymx, o, 64));
        }
        if (lane == 0) {
            dpart[w*5+0] = sx; dpart[w*5+1] = sy; dpart[w*5+2] = sxy;
            dpart[w*5+3] = sxx; dpart[w*5+4] = syy;
            fpart[w*4+0] = xmn; fpart[w*4+1] = xmx; fpart[w*4+2] = ymn; fpart[w*4+3] = ymx;
        }
    }
    for (int q = t; q < 400; q += 256) subhist[q] = 0;
    __syncthreads();
    if (t == 0) {
        double v0=0,v1=0,v2=0,v3=0,v4=0;
        float b0=fpart[0], b1=fpart[1], b2=fpart[2], b3=fpart[3];
        for (int q = 0; q < 4; ++q) {
            v0 += dpart[q*5]; v1 += dpart[q*5+1]; v2 += dpart[q*5+2];
            v3 += dpart[q*5+3]; v4 += dpart[q*5+4];
            b0 = fminf(b0, fpart[q*4]);   b1 = fmaxf(b1, fpart[q*4+1]);
            b2 = fminf(b2, fpart[q*4+2]); b3 = fmaxf(b3, fpart[q*4+3]);
        }
        double N = (double)SS;
        double num = N * v2 - v0 * v1;
        double den = sqrt((N * v3 - v0 * v0) * (N * v4 - v1 * v1));
        wpear[row] = (float)(1.0 - num / den);
        sbounds[0] = b0; sbounds[1] = b1; sbounds[2] = b2; sbounds[3] = b3;
    }
    __syncthreads();

    // ---- pass 2: histogram (re-read global; 4 per-wave sub-hists)
    {
        const float x0 = sbounds[0], bwx = (sbounds[1] - x0) / 10.0f;
        const float y0 = sbounds[2], bwy = (sbounds[3] - y0) / 10.0f;
        int* hsub = subhist + w * 100;
        for (int n = t; n < SS; n += 256) {
            int ix = (int)((x[n] - x0) / bwx); ix = min(max(ix, 0), 9);
            int iy = (int)((y[n] - y0) / bwy); iy = min(max(iy, 0), 9);
            atomicAdd(&hsub[ix * 10 + iy], 1);
        }
    }
    __syncthreads();
    if (t < 100) subhist[t] = subhist[t] + subhist[100+t] + subhist[200+t] + subhist[300+t];
    __syncthreads();
    if (t < 10) {
        int s1 = 0, s2 = 0;
        for (int j = 0; j < 10; ++j) { s1 += subhist[t*10+j]; s2 += subhist[j*10+t]; }
        hxm[t] = (float)s1; hym[t] = (float)s2;
    }
    __syncthreads();
    {
        float term = 0.0f;
        if (t < 100) {
            const float denom = 8388608.0f, eps = 1e-8f;
            float pxy = (float)subhist[t] / denom;
            float px = hxm[t / 10] / denom, py = hym[t % 10] / denom;
            term = pxy * logf((pxy + eps) / (px * py + eps));
        }
        if (t < 128) mterm[t] = (t < 100) ? term : 0.0f;
    }
    __syncthreads();
    if (t == 0) {
        const float denom = 8388608.0f, eps = 1e-8f;
        float mi = 0.0f;
        for (int q = 0; q < 100; ++q) mi += mterm[q];
        float hxe = 0.0f, hye = 0.0f;
        for (int q = 0; q < 10; ++q) {
            float px = hxm[q] / denom, py = hym[q] / denom;
            hxe -= px * logf(px + eps);
            hye -= py * logf(py + eps);
        }
        wnmi[row] = mi / (0.5f * (hxe + hye));
    }
}

// ---------------------------------------------------------------------------
// K2: all three FFTs per row (power fwd; phase fwd; inverse) + sums/argmax.
// ---------------------------------------------------------------------------
__global__ __launch_bounds__(1024) void k_fft(const float* __restrict__ pred,
                                              const float* __restrict__ targ,
                                              const int* __restrict__ ip,
                                              double* __restrict__ wnum,
                                              double* __restrict__ wden,
                                              float* __restrict__ wcos) {
    __shared__ float re[NPAD];
    __shared__ float im[NPAD];
    __shared__ double dpart[32];
    __shared__ float svalw[16];
    __shared__ int   sidxw[16];
    const int row = blockIdx.x;
    const int t = threadIdx.x;
    const int w = t >> 6;
    const int lane = t & 63;
    const float* xg = pred + (size_t)ip[0] * (size_t)BB * SS + (size_t)row * SS;
    const float* yg = targ + (size_t)row * SS;

    // ---- FFT1 (power): z = x + i*y, natural order in
    for (int m = 0; m < 16; ++m) {
        int n = t + (m << 10);
        re[PAD32(n)] = xg[n];
        im[PAD32(n)] = yg[n];
    }
    __syncthreads();
    stage_dif<-1, 14>(re, im, t);
    stage_dif<-1, 12>(re, im, t);
    stage_dif<-1, 10>(re, im, t);
    stage_dif<-1, 8>(re, im, t);
    stage_dif<-1, 6>(re, im, t);
    stage_dif<-1, 4>(re, im, t);
    stage_dif<-1, 2>(re, im, t);

    // ---- unpack packed-real spectra at digit-rev positions, power sums
    {
        double anum = 0.0, aden = 0.0;
        for (int m = 0; m < 8; ++m) {
            int k = t + (m << 10);
            int km = (SS - k) & (SS - 1);
            int q = PAD32(digrev4(k)), q2 = PAD32(digrev4(km));
            float ar = re[q], ai = im[q];
            float cr = re[q2], ci = im[q2];
            float xr = 0.5f * (ar + cr), xi = 0.5f * (ai - ci);
            float yr = 0.5f * (ai + ci), yi = 0.5f * (cr - ar);
            float xp = xr * xr + xi * xi;
            float tp = yr * yr + yi * yi;
            anum += (double)fabsf(xp - tp);
            aden += (double)tp;
        }
        if (t == 0) {   // k = 8192 (self-conjugate)
            int q = PAD32(digrev4(8192));
            float ar = re[q], ai = im[q];
            anum += (double)fabsf(ar * ar - ai * ai);
            aden += (double)(ai * ai);
        }
        #pragma unroll
        for (int o = 32; o > 0; o >>= 1) {
            anum += __shfl_down(anum, o, 64);
            aden += __shfl_down(aden, o, 64);
        }
        if (lane == 0) { dpart[w*2] = anum; dpart[w*2+1] = aden; }
    }
    __syncthreads();
    if (t == 0) {
        double a = 0, b = 0;
        for (int q = 0; q < 16; ++q) { a += dpart[q*2]; b += dpart[q*2+1]; }
        wnum[row] = a; wden[row] = b;
    }

    // ---- FFT2 (phase fwd): reload x,y (L3-hit), hann on the fly
    __syncthreads();   // all unpack reads complete before overwrite
    for (int m = 0; m < 16; ++m) {
        int n = t + (m << 10);
        float wv = 0.5f * (1.0f - __builtin_amdgcn_cosf((float)n * (1.0f / 16384.0f)));
        re[PAD32(n)] = xg[n] * wv;
        im[PAD32(n)] = yg[n] * wv;
    }
    __syncthreads();
    stage_dif<-1, 14>(re, im, t);
    stage_dif<-1, 12>(re, im, t);
    stage_dif<-1, 10>(re, im, t);
    stage_dif<-1, 8>(re, im, t);
    stage_dif<-1, 6>(re, im, t);
    stage_dif<-1, 4>(re, im, t);
    stage_dif<-1, 2>(re, im, t);

    // ---- unpack + phase-normalize at rev positions (self-contained pairs)
    {
        for (int m = 0; m < 8; ++m) {
            int k = t + (m << 10);
            int km = (SS - k) & (SS - 1);
            int q = PAD32(digrev4(k)), q2 = PAD32(digrev4(km));
            float ar = re[q], ai = im[q];
            float cr0 = re[q2], ci0 = im[q2];
            float xr = 0.5f * (ar + cr0), xi = 0.5f * (ai - ci0);
            float yr = 0.5f * (ai + ci0), yi = 0.5f * (cr0 - ar);
            float cr = xr * yr + xi * yi;
            float ci = xi * yr - xr * yi;
            float mag = sqrtf(cr * cr + ci * ci);
            cr /= mag; ci /= mag;
            re[q] = cr;  im[q] = ci;
            re[q2] = cr; im[q2] = -ci;
        }
        if (t == 0) {   // k = 8192
            int q = PAD32(digrev4(8192));
            float ar = re[q], ai = im[q];
            float cr = ar * ai;
            cr = cr / fabsf(cr);
            re[q] = cr; im[q] = 0.0f;
        }
    }
    __syncthreads();

    // ---- FFT3: inverse DIT (rev input -> natural output)
    stage_dit<1, 2>(re, im, t);
    stage_dit<1, 4>(re, im, t);
    stage_dit<1, 6>(re, im, t);
    stage_dit<1, 8>(re, im, t);
    stage_dit<1, 10>(re, im, t);
    stage_dit<1, 12>(re, im, t);
    stage_dit<1, 14>(re, im, t);

    // ---- argmax of real part, first-index tie-break
    {
        float bv = -1e30f; int bi = 0;
        for (int m = 0; m < 16; ++m) {
            int n = t + (m << 10);
            float v = re[PAD32(n)];
            if (v > bv) { bv = v; bi = n; }
        }
        #pragma unroll
        for (int o = 32; o > 0; o >>= 1) {
            float v2 = __shfl_down(bv, o, 64);
            int i2 = __shfl_down(bi, o, 64);
            if (v2 > bv || (v2 == bv && i2 < bi)) { bv = v2; bi = i2; }
        }
        if (lane == 0) { svalw[w] = bv; sidxw[w] = bi; }
    }
    __syncthreads();
    if (t == 0) {
        float bv = svalw[0]; int bi = sidxw[0];
        for (int q = 1; q < 16; ++q) {
            if (svalw[q] > bv || (svalw[q] == bv && sidxw[q] < bi)) { bv = svalw[q]; bi = sidxw[q]; }
        }
        wcos[row] = cosf(TPIF * (float)bi / 16384.0f);
    }
}

// ---------------------------------------------------------------------------
// Final combine (reads epoch on-device; graph-safe). Wave-shuffle reductions.
// ---------------------------------------------------------------------------
__global__ __launch_bounds__(512) void k_combine(const float* __restrict__ wpear,
                                                 const float* __restrict__ wcos,
                                                 const double* __restrict__ wnum,
                                                 const double* __restrict__ wden,
                                                 const float* __restrict__ wnmi,
                                                 const int* __restrict__ ep,
                                                 float* __restrict__ out) {
    __shared__ double dp[8 * 5];
    const int tid = threadIdx.x;
    const int w = tid >> 6, lane = tid & 63;
    double v0 = (double)wpear[tid], v1 = (double)wcos[tid];
    double v2 = wnum[tid], v3 = wden[tid], v4 = (double)wnmi[tid];
    #pragma unroll
    for (int o = 32; o > 0; o >>= 1) {
        v0 += __shfl_down(v0, o, 64); v1 += __shfl_down(v1, o, 64);
        v2 += __shfl_down(v2, o, 64); v3 += __shfl_down(v3, o, 64);
        v4 += __shfl_down(v4, o, 64);
    }
    if (lane == 0) {
        dp[w*5+0] = v0; dp[w*5+1] = v1; dp[w*5+2] = v2; dp[w*5+3] = v3; dp[w*5+4] = v4;
    }
    __syncthreads();
    if (tid == 0) {
        double s0=0,s1=0,s2=0,s3=0,s4=0;
        for (int q = 0; q < 8; ++q) {
            s0 += dp[q*5]; s1 += dp[q*5+1]; s2 += dp[q*5+2]; s3 += dp[q*5+3]; s4 += dp[q*5+4];
        }
        int epoch = ep[0];
        double loss = s0 / 512.0;
        if (epoch >= 400) {
            loss += 1.0 - s1 / 512.0;
            loss += s2 / s3;
        }
        if (epoch >= 700) {
            loss += 1.0 - s4 / 512.0;
        }
        out[0] = (float)loss;
    }
}

// ---------------------------------------------------------------------------
extern "C" void kernel_launch(void* const* d_in, const int* in_sizes, int n_in,
                              void* d_out, int out_size, void* d_ws, size_t ws_size,
                              hipStream_t stream) {
    const float* pred = (const float*)d_in[0];   // [2, 512, 16384] f32
    const float* targ = (const float*)d_in[1];   // [512, 16384] f32
    const int* ip = (const int*)d_in[2];         // scalar i
    const int* ep = (const int*)d_in[3];         // scalar epoch
    float* out = (float*)d_out;

    double* wnum = (double*)d_ws;                // [512]
    double* wden = wnum + BB;                    // [512]
    float* wpear = (float*)(wden + BB);          // [512]
    float* wcos = wpear + BB;                    // [512]
    float* wnmi = wcos + BB;                     // [512]

    k_stats<<<dim3(BB), dim3(256), 0, stream>>>(pred, targ, ip, wpear, wnmi);
    k_fft<<<dim3(BB), dim3(1024), 0, stream>>>(pred, targ, ip, wnum, wden, wcos);
    k_combine<<<dim3(1), dim3(512), 0, stream>>>(wpear, wcos, wnum, wden, wnmi, ep, out);
}

// Round 9
// 295.846 us; speedup vs baseline: 1.5038x; 1.5038x over previous
//
#include <hip/hip_runtime.h>
#include <math.h>

#define BB 512
#define SS 16384
#define TPIF 6.28318530717958647692f

// separate re/im float arrays in LDS; pad 1 per 32 elements
#define PAD32(i) ((i) + ((i) >> 5) + ((i) >> 10))
#define NPAD 16912   // PAD32(16383)=16909 < 16912

// base-4 digit reversal of 14-bit index (7 digits)
__device__ __forceinline__ int digrev4(int n) {
    unsigned x = __brev((unsigned)n) >> (32 - 14);
    return (int)(((x & 0x1555u) << 1) | ((x >> 1) & 0x1555u));
}

// ---------------------------------------------------------------------------
// Radix-4 stages as __noinline__ functions with RUNTIME loops.
// R2 (runtime loops, 52 VGPR, no spill) vs R7/R8 (templated full unroll,
// 64 VGPR + ~400 MB scratch spill): the unrolled 21-stage straight-line body
// lets the compiler hoist ~300 loop-invariant LDS addresses into live ranges
// that spill-fill around every barrier. __noinline__ + runtime `lg` forces
// compact code and kills cross-stage hoisting.
// DIF: lg descending 14..2, twiddle W_L^p on outputs -> digit-rev output.
// DIT: lg ascending 2..14, twiddle W_L^p on inputs, rev input -> natural.
// (math verified end-to-end in R7/R8, absmax 0.0)
// ---------------------------------------------------------------------------
__device__ __noinline__ void stage_dif(float* re, float* im, int t, int lg) {
    const int Q = 1 << (lg - 2);
    const float tw = -1.0f / (float)(Q << 2);   // revolutions per p, fwd sign
    for (int b = t; b < (SS >> 2); b += 1024) {
        const int p = b & (Q - 1);
        const int i0 = ((b >> (lg - 2)) << lg) + p;
        const int a0 = PAD32(i0), a1 = PAD32(i0 + Q), a2 = PAD32(i0 + 2 * Q), a3 = PAD32(i0 + 3 * Q);
        float z0r = re[a0], z0i = im[a0];
        float z1r = re[a1], z1i = im[a1];
        float z2r = re[a2], z2i = im[a2];
        float z3r = re[a3], z3i = im[a3];
        float t0r = z0r + z2r, t0i = z0i + z2i;
        float t1r = z0r - z2r, t1i = z0i - z2i;
        float t2r = z1r + z3r, t2i = z1i + z3i;
        float t3r = z1r - z3r, t3i = z1i - z3i;
        float b0r = t0r + t2r, b0i = t0i + t2i;
        float b2r = t0r - t2r, b2i = t0i - t2i;
        float b1r = t1r + t3i, b1i = t1i - t3r;   // sg = -1
        float b3r = t1r - t3i, b3i = t1i + t3r;
        const float arev = tw * (float)p;
        const float c1 = __builtin_amdgcn_cosf(arev);
        const float s1 = __builtin_amdgcn_sinf(arev);
        const float c2 = c1 * c1 - s1 * s1, s2 = 2.0f * c1 * s1;
        const float c3 = c1 * c2 - s1 * s2, s3 = c1 * s2 + s1 * c2;
        re[a0] = b0r;                    im[a0] = b0i;
        re[a1] = b1r * c1 - b1i * s1;    im[a1] = b1r * s1 + b1i * c1;
        re[a2] = b2r * c2 - b2i * s2;    im[a2] = b2r * s2 + b2i * c2;
        re[a3] = b3r * c3 - b3i * s3;    im[a3] = b3r * s3 + b3i * c3;
    }
    __syncthreads();
}

__device__ __noinline__ void stage_dit(float* re, float* im, int t, int lg) {
    const int Q = 1 << (lg - 2);
    const float tw = 1.0f / (float)(Q << 2);    // inverse sign
    for (int b = t; b < (SS >> 2); b += 1024) {
        const int p = b & (Q - 1);
        const int i0 = ((b >> (lg - 2)) << lg) + p;
        const int a0 = PAD32(i0), a1 = PAD32(i0 + Q), a2 = PAD32(i0 + 2 * Q), a3 = PAD32(i0 + 3 * Q);
        float z0r = re[a0], z0i = im[a0];
        float z1r = re[a1], z1i = im[a1];
        float z2r = re[a2], z2i = im[a2];
        float z3r = re[a3], z3i = im[a3];
        const float arev = tw * (float)p;
        const float c1 = __builtin_amdgcn_cosf(arev);
        const float s1 = __builtin_amdgcn_sinf(arev);
        const float c2 = c1 * c1 - s1 * s1, s2 = 2.0f * c1 * s1;
        const float c3 = c1 * c2 - s1 * s2, s3 = c1 * s2 + s1 * c2;
        float a1r = z1r * c1 - z1i * s1, a1i = z1r * s1 + z1i * c1;
        float a2r = z2r * c2 - z2i * s2, a2i = z2r * s2 + z2i * c2;
        float a3r = z3r * c3 - z3i * s3, a3i = z3r * s3 + z3i * c3;
        float t0r = z0r + a2r, t0i = z0i + a2i;
        float t1r = z0r - a2r, t1i = z0i - a2i;
        float t2r = a1r + a3r, t2i = a1i + a3i;
        float t3r = a1r - a3r, t3i = a1i - a3i;
        re[a0] = t0r + t2r;   im[a0] = t0i + t2i;
        re[a2] = t0r - t2r;   im[a2] = t0i - t2i;
        re[a1] = t1r - t3i;   im[a1] = t1i + t3r;   // sg = +1
        re[a3] = t1r + t3i;   im[a3] = t1i - t3r;
    }
    __syncthreads();
}

// ---------------------------------------------------------------------------
// K1: Pearson + MI per row (256 threads; R1-proven structure, two passes
// over global data, second pass L3-resident)
// ---------------------------------------------------------------------------
__global__ __launch_bounds__(256) void k_stats(const float* __restrict__ pred,
                                               const float* __restrict__ targ,
                                               const int* __restrict__ ip,
                                               float* __restrict__ wpear,
                                               float* __restrict__ wnmi) {
    __shared__ double dpart[4 * 5];
    __shared__ float fpart[4 * 4];
    __shared__ float sbounds[4];
    __shared__ int   subhist[400];
    __shared__ float hxm[10], hym[10];
    __shared__ float mterm[128];
    const int row = blockIdx.x;
    const int t = threadIdx.x;
    const int w = t >> 6;
    const int lane = t & 63;
    const float* x = pred + (size_t)ip[0] * (size_t)BB * SS + (size_t)row * SS;
    const float* y = targ + (size_t)row * SS;

    // ---- pass 1: Pearson sums (fp64) + min/max
    {
        double sx = 0, sy = 0, sxy = 0, sxx = 0, syy = 0;
        float xmn = 1e30f, xmx = -1e30f, ymn = 1e30f, ymx = -1e30f;
        for (int n = t; n < SS; n += 256) {
            float a = x[n], b = y[n];
            sx += (double)a; sy += (double)b;
            sxy += (double)a * (double)b;
            sxx += (double)a * (double)a;
            syy += (double)b * (double)b;
            xmn = fminf(xmn, a); xmx = fmaxf(xmx, a);
            ymn = fminf(ymn, b); ymx = fmaxf(ymx, b);
        }
        #pragma unroll
        for (int o = 32; o > 0; o >>= 1) {
            sx += __shfl_down(sx, o, 64);  sy += __shfl_down(sy, o, 64);
            sxy += __shfl_down(sxy, o, 64);
            sxx += __shfl_down(sxx, o, 64); syy += __shfl_down(syy, o, 64);
            xmn = fminf(xmn, __shfl_down(xmn, o, 64));
            xmx = fmaxf(xmx, __shfl_down(xmx, o, 64));
            ymn = fminf(ymn, __shfl_down(ymn, o, 64));
            ymx = fmaxf(ymx, __shfl_down(ymx, o, 64));
        }
        if (lane == 0) {
            dpart[w*5+0] = sx; dpart[w*5+1] = sy; dpart[w*5+2] = sxy;
            dpart[w*5+3] = sxx; dpart[w*5+4] = syy;
            fpart[w*4+0] = xmn; fpart[w*4+1] = xmx; fpart[w*4+2] = ymn; fpart[w*4+3] = ymx;
        }
    }
    for (int q = t; q < 400; q += 256) subhist[q] = 0;
    __syncthreads();
    if (t == 0) {
        double v0=0,v1=0,v2=0,v3=0,v4=0;
        float b0=fpart[0], b1=fpart[1], b2=fpart[2], b3=fpart[3];
        for (int q = 0; q < 4; ++q) {
            v0 += dpart[q*5]; v1 += dpart[q*5+1]; v2 += dpart[q*5+2];
            v3 += dpart[q*5+3]; v4 += dpart[q*5+4];
            b0 = fminf(b0, fpart[q*4]);   b1 = fmaxf(b1, fpart[q*4+1]);
            b2 = fminf(b2, fpart[q*4+2]); b3 = fmaxf(b3, fpart[q*4+3]);
        }
        double N = (double)SS;
        double num = N * v2 - v0 * v1;
        double den = sqrt((N * v3 - v0 * v0) * (N * v4 - v1 * v1));
        wpear[row] = (float)(1.0 - num / den);
        sbounds[0] = b0; sbounds[1] = b1; sbounds[2] = b2; sbounds[3] = b3;
    }
    __syncthreads();

    // ---- pass 2: histogram (re-read global; 4 per-wave sub-hists)
    {
        const float x0 = sbounds[0], bwx = (sbounds[1] - x0) / 10.0f;
        const float y0 = sbounds[2], bwy = (sbounds[3] - y0) / 10.0f;
        int* hsub = subhist + w * 100;
        for (int n = t; n < SS; n += 256) {
            int ix = (int)((x[n] - x0) / bwx); ix = min(max(ix, 0), 9);
            int iy = (int)((y[n] - y0) / bwy); iy = min(max(iy, 0), 9);
            atomicAdd(&hsub[ix * 10 + iy], 1);
        }
    }
    __syncthreads();
    if (t < 100) subhist[t] = subhist[t] + subhist[100+t] + subhist[200+t] + subhist[300+t];
    __syncthreads();
    if (t < 10) {
        int s1 = 0, s2 = 0;
        for (int j = 0; j < 10; ++j) { s1 += subhist[t*10+j]; s2 += subhist[j*10+t]; }
        hxm[t] = (float)s1; hym[t] = (float)s2;
    }
    __syncthreads();
    {
        float term = 0.0f;
        if (t < 100) {
            const float denom = 8388608.0f, eps = 1e-8f;
            float pxy = (float)subhist[t] / denom;
            float px = hxm[t / 10] / denom, py = hym[t % 10] / denom;
            term = pxy * logf((pxy + eps) / (px * py + eps));
        }
        if (t < 128) mterm[t] = (t < 100) ? term : 0.0f;
    }
    __syncthreads();
    if (t == 0) {
        const float denom = 8388608.0f, eps = 1e-8f;
        float mi = 0.0f;
        for (int q = 0; q < 100; ++q) mi += mterm[q];
        float hxe = 0.0f, hye = 0.0f;
        for (int q = 0; q < 10; ++q) {
            float px = hxm[q] / denom, py = hym[q] / denom;
            hxe -= px * logf(px + eps);
            hye -= py * logf(py + eps);
        }
        wnmi[row] = mi / (0.5f * (hxe + hye));
    }
}

// ---------------------------------------------------------------------------
// K2: all three FFTs per row (power fwd; phase fwd; inverse) + sums/argmax.
// ---------------------------------------------------------------------------
__global__ __launch_bounds__(1024) void k_fft(const float* __restrict__ pred,
                                              const float* __restrict__ targ,
                                              const int* __restrict__ ip,
                                              double* __restrict__ wnum,
                                              double* __restrict__ wden,
                                              float* __restrict__ wcos) {
    __shared__ float re[NPAD];
    __shared__ float im[NPAD];
    __shared__ double dpart[32];
    __shared__ float svalw[16];
    __shared__ int   sidxw[16];
    const int row = blockIdx.x;
    const int t = threadIdx.x;
    const int w = t >> 6;
    const int lane = t & 63;
    const float* xg = pred + (size_t)ip[0] * (size_t)BB * SS + (size_t)row * SS;
    const float* yg = targ + (size_t)row * SS;

    // ---- FFT1 (power): z = x + i*y, natural order in
    for (int n = t; n < SS; n += 1024) {
        re[PAD32(n)] = xg[n];
        im[PAD32(n)] = yg[n];
    }
    __syncthreads();
    for (int lg = 14; lg >= 2; lg -= 2) stage_dif(re, im, t, lg);

    // ---- unpack packed-real spectra at digit-rev positions, power sums
    {
        double anum = 0.0, aden = 0.0;
        for (int k = t; k < (SS >> 1); k += 1024) {
            int km = (SS - k) & (SS - 1);
            int q = PAD32(digrev4(k)), q2 = PAD32(digrev4(km));
            float ar = re[q], ai = im[q];
            float cr = re[q2], ci = im[q2];
            float xr = 0.5f * (ar + cr), xi = 0.5f * (ai - ci);
            float yr = 0.5f * (ai + ci), yi = 0.5f * (cr - ar);
            float xp = xr * xr + xi * xi;
            float tp = yr * yr + yi * yi;
            anum += (double)fabsf(xp - tp);
            aden += (double)tp;
        }
        if (t == 0) {   // k = 8192 (self-conjugate)
            int q = PAD32(digrev4(8192));
            float ar = re[q], ai = im[q];
            anum += (double)fabsf(ar * ar - ai * ai);
            aden += (double)(ai * ai);
        }
        #pragma unroll
        for (int o = 32; o > 0; o >>= 1) {
            anum += __shfl_down(anum, o, 64);
            aden += __shfl_down(aden, o, 64);
        }
        if (lane == 0) { dpart[w*2] = anum; dpart[w*2+1] = aden; }
    }
    __syncthreads();
    if (t == 0) {
        double a = 0, b = 0;
        for (int q = 0; q < 16; ++q) { a += dpart[q*2]; b += dpart[q*2+1]; }
        wnum[row] = a; wden[row] = b;
    }

    // ---- FFT2 (phase fwd): reload x,y (L3-hit), hann on the fly
    __syncthreads();   // all unpack reads complete before overwrite
    for (int n = t; n < SS; n += 1024) {
        float wv = 0.5f * (1.0f - __builtin_amdgcn_cosf((float)n * (1.0f / 16384.0f)));
        re[PAD32(n)] = xg[n] * wv;
        im[PAD32(n)] = yg[n] * wv;
    }
    __syncthreads();
    for (int lg = 14; lg >= 2; lg -= 2) stage_dif(re, im, t, lg);

    // ---- unpack + phase-normalize at rev positions (self-contained pairs)
    {
        for (int k = t; k < (SS >> 1); k += 1024) {
            int km = (SS - k) & (SS - 1);
            int q = PAD32(digrev4(k)), q2 = PAD32(digrev4(km));
            float ar = re[q], ai = im[q];
            float cr0 = re[q2], ci0 = im[q2];
            float xr = 0.5f * (ar + cr0), xi = 0.5f * (ai - ci0);
            float yr = 0.5f * (ai + ci0), yi = 0.5f * (cr0 - ar);
            float cr = xr * yr + xi * yi;
            float ci = xi * yr - xr * yi;
            float mag = sqrtf(cr * cr + ci * ci);
            cr /= mag; ci /= mag;
            re[q] = cr;  im[q] = ci;
            re[q2] = cr; im[q2] = -ci;
        }
        if (t == 0) {   // k = 8192
            int q = PAD32(digrev4(8192));
            float ar = re[q], ai = im[q];
            float cr = ar * ai;
            cr = cr / fabsf(cr);
            re[q] = cr; im[q] = 0.0f;
        }
    }
    __syncthreads();

    // ---- FFT3: inverse DIT (rev input -> natural output)
    for (int lg = 2; lg <= 14; lg += 2) stage_dit(re, im, t, lg);

    // ---- argmax of real part, first-index tie-break
    {
        float bv = -1e30f; int bi = 0;
        for (int n = t; n < SS; n += 1024) {
            float v = re[PAD32(n)];
            if (v > bv) { bv = v; bi = n; }
        }
        #pragma unroll
        for (int o = 32; o > 0; o >>= 1) {
            float v2 = __shfl_down(bv, o, 64);
            int i2 = __shfl_down(bi, o, 64);
            if (v2 > bv || (v2 == bv && i2 < bi)) { bv = v2; bi = i2; }
        }
        if (lane == 0) { svalw[w] = bv; sidxw[w] = bi; }
    }
    __syncthreads();
    if (t == 0) {
        float bv = svalw[0]; int bi = sidxw[0];
        for (int q = 1; q < 16; ++q) {
            if (svalw[q] > bv || (svalw[q] == bv && sidxw[q] < bi)) { bv = svalw[q]; bi = sidxw[q]; }
        }
        wcos[row] = cosf(TPIF * (float)bi / 16384.0f);
    }
}

// ---------------------------------------------------------------------------
// Final combine (reads epoch on-device; graph-safe). Wave-shuffle reductions.
// ---------------------------------------------------------------------------
__global__ __launch_bounds__(512) void k_combine(const float* __restrict__ wpear,
                                                 const float* __restrict__ wcos,
                                                 const double* __restrict__ wnum,
                                                 const double* __restrict__ wden,
                                                 const float* __restrict__ wnmi,
                                                 const int* __restrict__ ep,
                                                 float* __restrict__ out) {
    __shared__ double dp[8 * 5];
    const int tid = threadIdx.x;
    const int w = tid >> 6, lane = tid & 63;
    double v0 = (double)wpear[tid], v1 = (double)wcos[tid];
    double v2 = wnum[tid], v3 = wden[tid], v4 = (double)wnmi[tid];
    #pragma unroll
    for (int o = 32; o > 0; o >>= 1) {
        v0 += __shfl_down(v0, o, 64); v1 += __shfl_down(v1, o, 64);
        v2 += __shfl_down(v2, o, 64); v3 += __shfl_down(v3, o, 64);
        v4 += __shfl_down(v4, o, 64);
    }
    if (lane == 0) {
        dp[w*5+0] = v0; dp[w*5+1] = v1; dp[w*5+2] = v2; dp[w*5+3] = v3; dp[w*5+4] = v4;
    }
    __syncthreads();
    if (tid == 0) {
        double s0=0,s1=0,s2=0,s3=0,s4=0;
        for (int q = 0; q < 8; ++q) {
            s0 += dp[q*5]; s1 += dp[q*5+1]; s2 += dp[q*5+2]; s3 += dp[q*5+3]; s4 += dp[q*5+4];
        }
        int epoch = ep[0];
        double loss = s0 / 512.0;
        if (epoch >= 400) {
            loss += 1.0 - s1 / 512.0;
            loss += s2 / s3;
        }
        if (epoch >= 700) {
            loss += 1.0 - s4 / 512.0;
        }
        out[0] = (float)loss;
    }
}

// ---------------------------------------------------------------------------
extern "C" void kernel_launch(void* const* d_in, const int* in_sizes, int n_in,
                              void* d_out, int out_size, void* d_ws, size_t ws_size,
                              hipStream_t stream) {
    const float* pred = (const float*)d_in[0];   // [2, 512, 16384] f32
    const float* targ = (const float*)d_in[1];   // [512, 16384] f32
    const int* ip = (const int*)d_in[2];         // scalar i
    const int* ep = (const int*)d_in[3];         // scalar epoch
    float* out = (float*)d_out;

    double* wnum = (double*)d_ws;                // [512]
    double* wden = wnum + BB;                    // [512]
    float* wpear = (float*)(wden + BB);          // [512]
    float* wcos = wpear + BB;                    // [512]
    float* wnmi = wcos + BB;                     // [512]

    k_stats<<<dim3(BB), dim3(256), 0, stream>>>(pred, targ, ip, wpear, wnmi);
    k_fft<<<dim3(BB), dim3(1024), 0, stream>>>(pred, targ, ip, wnum, wden, wcos);
    k_combine<<<dim3(1), dim3(512), 0, stream>>>(wpear, wcos, wnum, wden, wnmi, ep, out);
}